// Round 1
// baseline (87.467 us; speedup 1.0000x reference)
//
#include <hip/hip_runtime.h>
#include <math.h>

#define E 256
#define R 16
#define F 64

__device__ __forceinline__ float eluf(float x) {
  return x > 0.f ? x : expm1f(x);
}

// ---------------------------------------------------------------------------
// K1: s[i,j,k] = softmax_j(adj[i,j,k]).  One block per i. adj row = 4096 f32.
// LDS layout [j][k] padded to stride 17 to dodge bank conflicts on the
// strided (k-fixed) reads.
// ---------------------------------------------------------------------------
__global__ __launch_bounds__(256) void k1_adj_softmax(const float* __restrict__ adj,
                                                      float* __restrict__ s) {
  __shared__ float lds[256 * 17];
  __shared__ float red[256];
  __shared__ float mk[16], sk[16];
  const int i = blockIdx.x;
  const int t = threadIdx.x;
  const float* a = adj + i * 4096;
  // load (coalesced), scatter into padded [j][k]
  for (int q = 0; q < 16; ++q) {
    int l = q * 256 + t;                 // l = j*16 + k
    lds[(l >> 4) * 17 + (l & 15)] = a[l];
  }
  __syncthreads();
  const int k = t & 15, g = t >> 4;      // g: 16 j-groups of 16
  float m = -INFINITY;
  #pragma unroll
  for (int jj = 0; jj < 16; ++jj) m = fmaxf(m, lds[(g * 16 + jj) * 17 + k]);
  red[k * 16 + g] = m;
  __syncthreads();
  if (t < 16) {
    float mm = red[t * 16];
    for (int g2 = 1; g2 < 16; ++g2) mm = fmaxf(mm, red[t * 16 + g2]);
    mk[t] = mm;
  }
  __syncthreads();
  const float mm = mk[k];
  float ssum = 0.f;
  #pragma unroll
  for (int jj = 0; jj < 16; ++jj) {
    int idx = (g * 16 + jj) * 17 + k;
    float v = __expf(lds[idx] - mm);
    lds[idx] = v;                        // cache exp for the write pass
    ssum += v;
  }
  red[k * 16 + g] = ssum;
  __syncthreads();
  if (t < 16) {
    float ss = 0.f;
    for (int g2 = 0; g2 < 16; ++g2) ss += red[t * 16 + g2];
    sk[t] = 1.f / ss;
  }
  __syncthreads();
  float* so = s + i * 4096;
  for (int q = 0; q < 16; ++q) {
    int l = q * 256 + t;
    int kk = l & 15;
    so[l] = lds[(l >> 4) * 17 + kk] * sk[kk];   // coalesced store
  }
}

// ---------------------------------------------------------------------------
// K2: attention[j,k,f] = 0.6*c*P + 0.4*|c|*Q,
//     P[k,f] = sum_i s[i,j,k]*h[i,f], Q with |h|, c = h[j,f]*r[k,f].
// One block per j, 256 threads = (kg:4) x (ig:4) x (fg:16); each thread owns
// a 4k x 4f tile over a 64-long i quarter; LDS reduction across ig.
// ---------------------------------------------------------------------------
__global__ __launch_bounds__(256) void k2_contract(const float* __restrict__ h,
                                                   const float* __restrict__ r,
                                                   const float* __restrict__ s,
                                                   float* __restrict__ att) {
  __shared__ float hl[E * F];            // 64 KB  [i][f]
  __shared__ float sl[E * R];            // 16 KB  [i][k]
  __shared__ float redp[4 * 16 * 4 * 17];  // 17 KB, stride-17 padded
  __shared__ float redq[4 * 16 * 4 * 17];  // 17 KB
  const int j = blockIdx.x;
  const int t = threadIdx.x;

  float4* hl4 = (float4*)hl;
  const float4* h4 = (const float4*)h;
  #pragma unroll
  for (int q = 0; q < 16; ++q) hl4[q * 256 + t] = h4[q * 256 + t];
  float4* sl4 = (float4*)sl;
  const float4* s4 = (const float4*)s;
  #pragma unroll
  for (int q = 0; q < 4; ++q) {
    int c = q * 256 + t;                 // c = i*4 + kq
    sl4[c] = s4[(c >> 2) * 1024 + j * 4 + (c & 3)];
  }
  __syncthreads();

  const int kg = t >> 6;                 // k = kg*4 + kk
  const int ig = (t >> 4) & 3;           // i quarter
  const int fg = t & 15;                 // f = fg*4 + ff
  float p[4][4] = {{0.f}};
  float qa[4][4] = {{0.f}};
  const int ibase = ig * 64;
  for (int ii = 0; ii < 64; ++ii) {
    const int i = ibase + ii;
    const float4 hv = *(const float4*)&hl[i * F + fg * 4];
    const float4 sv = *(const float4*)&sl[i * R + kg * 4];
    const float hvv[4] = {hv.x, hv.y, hv.z, hv.w};
    const float hav[4] = {fabsf(hv.x), fabsf(hv.y), fabsf(hv.z), fabsf(hv.w)};
    const float svv[4] = {sv.x, sv.y, sv.z, sv.w};
    #pragma unroll
    for (int kk = 0; kk < 4; ++kk) {
      #pragma unroll
      for (int ff = 0; ff < 4; ++ff) {
        p[kk][ff]  = fmaf(svv[kk], hvv[ff], p[kk][ff]);
        qa[kk][ff] = fmaf(svv[kk], hav[ff], qa[kk][ff]);
      }
    }
  }
  // spill partials (stride-17 over the ig axis)
  {
    float* rp = &redp[((kg * 16 + fg) * 4 + ig) * 17];
    float* rq = &redq[((kg * 16 + fg) * 4 + ig) * 17];
    #pragma unroll
    for (int kk = 0; kk < 4; ++kk)
      #pragma unroll
      for (int ff = 0; ff < 4; ++ff) {
        rp[kk * 4 + ff] = p[kk][ff];
        rq[kk * 4 + ff] = qa[kk][ff];
      }
  }
  __syncthreads();
  // finalize: 4 (k,f) outputs per thread
  #pragma unroll
  for (int qq = 0; qq < 4; ++qq) {
    const int kf = qq * 256 + t;
    const int k = kf >> 6, f = kf & 63;
    const int base = ((k >> 2) * 16 + (f >> 2)) * 4 * 17 + (k & 3) * 4 + (f & 3);
    float pv = redp[base] + redp[base + 17] + redp[base + 34] + redp[base + 51];
    float qv = redq[base] + redq[base + 17] + redq[base + 34] + redq[base + 51];
    const float c = hl[j * F + f] * r[k * F + f];
    att[j * 1024 + kf] = 0.6f * c * pv + 0.4f * fabsf(c) * qv;
  }
}

// ---------------------------------------------------------------------------
// K3: per e: softmax over k -> aR[e,k,f];  lin[e,k] = sum_f aR*w[f] + b.
// Block per e; wave w handles k = w*4..w*4+3; lanes = f.
// ---------------------------------------------------------------------------
__global__ __launch_bounds__(256) void k3_rowsoft(const float* __restrict__ att,
                                                  const float* __restrict__ w,
                                                  const float* __restrict__ b,
                                                  float* __restrict__ aR,
                                                  float* __restrict__ lin) {
  const int e = blockIdx.x;
  const int t = threadIdx.x;
  const int f = t & 63;
  const int wv = t >> 6;
  const float* ar = att + e * 1024;
  float av[16];
  #pragma unroll
  for (int k = 0; k < 16; ++k) av[k] = ar[k * 64 + f];   // coalesced per k
  float m = -INFINITY;
  #pragma unroll
  for (int k = 0; k < 16; ++k) m = fmaxf(m, av[k]);
  float ssum = 0.f;
  float ex[16];
  #pragma unroll
  for (int k = 0; k < 16; ++k) { ex[k] = __expf(av[k] - m); ssum += ex[k]; }
  const float inv = 1.f / ssum;
  const float wf = w[f];
  const float bb = b[0];
  #pragma unroll
  for (int mq = 0; mq < 4; ++mq) {
    const int k = wv * 4 + mq;
    const float a = ex[k] * inv;
    aR[e * 1024 + k * 64 + f] = a;
    float v = a * wf;
    #pragma unroll
    for (int off = 32; off; off >>= 1) v += __shfl_xor(v, off, 64);
    if (f == 0) lin[e * 16 + k] = v + bb;
  }
}

// ---------------------------------------------------------------------------
// K4: blocks 0..1023: per (k,f): M,1/S over e (for attention_E) and
//     r_prime[k,f] = elu(r[k,f] * sum_e aR[e,k,f])  -> out.
//     blocks 1024..1039: alpha row a = softmax(lin[a*256 .. +256]) -> out.
// ---------------------------------------------------------------------------
__global__ __launch_bounds__(64) void k4_stats(const float* __restrict__ att,
                                               const float* __restrict__ aR,
                                               const float* __restrict__ lin,
                                               const float* __restrict__ r,
                                               float* __restrict__ M,
                                               float* __restrict__ Sinv,
                                               float* __restrict__ out) {
  const int bid = blockIdx.x;
  const int l = threadIdx.x;
  if (bid < 1024) {
    const int kf = bid;
    float v[4];
    #pragma unroll
    for (int q = 0; q < 4; ++q) v[q] = att[(l + q * 64) * 1024 + kf];
    float m = fmaxf(fmaxf(v[0], v[1]), fmaxf(v[2], v[3]));
    #pragma unroll
    for (int off = 32; off; off >>= 1) m = fmaxf(m, __shfl_xor(m, off, 64));
    float ssum = 0.f;
    #pragma unroll
    for (int q = 0; q < 4; ++q) ssum += __expf(v[q] - m);
    #pragma unroll
    for (int off = 32; off; off >>= 1) ssum += __shfl_xor(ssum, off, 64);
    float rs = 0.f;
    #pragma unroll
    for (int q = 0; q < 4; ++q) rs += aR[(l + q * 64) * 1024 + kf];
    #pragma unroll
    for (int off = 32; off; off >>= 1) rs += __shfl_xor(rs, off, 64);
    if (l == 0) {
      M[kf] = m;
      Sinv[kf] = 1.f / ssum;
      out[16384 + kf] = eluf(r[kf] * rs);
    }
  } else {
    const int a = bid - 1024;
    const float* lrow = lin + a * 256;
    float v[4];
    #pragma unroll
    for (int q = 0; q < 4; ++q) v[q] = lrow[l + q * 64];
    float m = fmaxf(fmaxf(v[0], v[1]), fmaxf(v[2], v[3]));
    #pragma unroll
    for (int off = 32; off; off >>= 1) m = fmaxf(m, __shfl_xor(m, off, 64));
    float ssum = 0.f;
    float ex[4];
    #pragma unroll
    for (int q = 0; q < 4; ++q) { ex[q] = __expf(v[q] - m); ssum += ex[q]; }
    #pragma unroll
    for (int off = 32; off; off >>= 1) ssum += __shfl_xor(ssum, off, 64);
    const float inv = 1.f / ssum;
    #pragma unroll
    for (int q = 0; q < 4; ++q) out[17408 + a * 256 + l + q * 64] = ex[q] * inv;
  }
}

// ---------------------------------------------------------------------------
// K5: h_prime[e,f] = elu( h[e,f] * sum_k exp(att[e,k,f]-M[k,f]) * Sinv[k,f] )
// ---------------------------------------------------------------------------
__global__ __launch_bounds__(256) void k5_hprime(const float* __restrict__ att,
                                                 const float* __restrict__ h,
                                                 const float* __restrict__ M,
                                                 const float* __restrict__ Sinv,
                                                 float* __restrict__ out) {
  const int n = blockIdx.x * 256 + threadIdx.x;   // 0..16383
  const int e = n >> 6, f = n & 63;
  float ssum = 0.f;
  #pragma unroll
  for (int k = 0; k < 16; ++k) {
    const int kf = k * 64 + f;
    ssum += __expf(att[e * 1024 + kf] - M[kf]) * Sinv[kf];
  }
  out[n] = eluf(h[n] * ssum);
}

extern "C" void kernel_launch(void* const* d_in, const int* in_sizes, int n_in,
                              void* d_out, int out_size, void* d_ws, size_t ws_size,
                              hipStream_t stream) {
  (void)in_sizes; (void)n_in; (void)out_size; (void)ws_size;
  const float* h   = (const float*)d_in[0];   // (256,64)
  const float* r   = (const float*)d_in[1];   // (16,64)
  const float* adj = (const float*)d_in[2];   // (256,256,16)
  const float* w   = (const float*)d_in[3];   // (1,64)
  const float* b   = (const float*)d_in[4];   // (1,)
  float* out = (float*)d_out;                 // 16384 + 1024 + 4096 = 21504

  float* ws   = (float*)d_ws;
  float* s    = ws;                    // 1,048,576 f32 (4 MB)
  float* aR   = ws;                    // reuses s region (s dead after K2)
  float* att  = ws + 1048576;          // 262,144 f32 (1 MB)
  float* lin  = ws + 1310720;          // 4,096 f32
  float* M    = ws + 1314816;          // 1,024 f32
  float* Sinv = ws + 1315840;          // 1,024 f32
  // total: 5,267,456 bytes of ws

  hipLaunchKernelGGL(k1_adj_softmax, dim3(256),  dim3(256), 0, stream, adj, s);
  hipLaunchKernelGGL(k2_contract,    dim3(256),  dim3(256), 0, stream, h, r, s, att);
  hipLaunchKernelGGL(k3_rowsoft,     dim3(256),  dim3(256), 0, stream, att, w, b, aR, lin);
  hipLaunchKernelGGL(k4_stats,       dim3(1040), dim3(64),  0, stream, att, aR, lin, r, M, Sinv, out);
  hipLaunchKernelGGL(k5_hprime,      dim3(64),   dim3(256), 0, stream, att, h, M, Sinv, out);
}